// Round 4
// baseline (315.965 us; speedup 1.0000x reference)
//
#include <hip/hip_runtime.h>
#include <hip/hip_bf16.h>
#include <stdint.h>
#include <stddef.h>

#define HH_EPS 1e-8f

typedef __attribute__((ext_vector_type(8))) short short8;
typedef __attribute__((ext_vector_type(4))) float f32x4;

#define CDIM 512
#define SDIM 4096
#define BN 64
#define BK 32
#define NSTEP 16      // CDIM / BK

// ---------------------------------------------------------------------------
// Frag-tiled W (blocking-agnostic): fragment id = (c>>5)*32 + (o>>4);
// within a fragment: lane = ((c>>3)&3)*16 + (o&15), elem = c&7.
// Fragment = 64 lanes x 16 B = 1 KB contiguous in exact B-operand lane order
// -> one dwordx4 per lane loads a whole MFMA B-fragment (no LDS needed).
// ---------------------------------------------------------------------------
__device__ __forceinline__ size_t wt_idx(int o, int c) {
    return (((size_t)(c >> 5) * 32 + (o >> 4)) * 64
            + (size_t)((c >> 3) & 3) * 16 + (o & 15)) * 8 + (c & 7);
}

// ---------------------------------------------------------------------------
// Kernel 1: W = H_32 ... H_1, column-parallel, on-the-fly normalization.
// ---------------------------------------------------------------------------
__global__ void compute_w(const float* __restrict__ V,
                          __hip_bfloat16* __restrict__ Wt) {
    const int wave = threadIdx.x >> 6;
    const int lane = threadIdx.x & 63;
    const int jA = (blockIdx.x * 4 + wave) * 2;
    const int jB = jA + 1;
    const int ib = lane * 8;

    float wA[8], wB[8];
    #pragma unroll
    for (int r = 0; r < 8; r++) {
        wA[r] = (ib + r == jA) ? 1.0f : 0.0f;
        wB[r] = (ib + r == jB) ? 1.0f : 0.0f;
    }
    float4 c0 = *(const float4*)(V + ib);
    float4 c1 = *(const float4*)(V + ib + 4);

    for (int k = 0; k < 32; k++) {
        const float v[8] = {c0.x, c0.y, c0.z, c0.w, c1.x, c1.y, c1.z, c1.w};
        if (k < 31) {
            c0 = *(const float4*)(V + (size_t)(k + 1) * 512 + ib);
            c1 = *(const float4*)(V + (size_t)(k + 1) * 512 + ib + 4);
        }
        float dA = 0.0f, dB = 0.0f, ss = 0.0f;
        #pragma unroll
        for (int r = 0; r < 8; r++) {
            dA += v[r] * wA[r];
            dB += v[r] * wB[r];
            ss += v[r] * v[r];
        }
        #pragma unroll
        for (int off = 32; off > 0; off >>= 1) {
            dA += __shfl_xor(dA, off);
            dB += __shfl_xor(dB, off);
            ss += __shfl_xor(ss, off);
        }
        const float t = sqrtf(ss) + HH_EPS;
        const float scale = 2.0f / (t * t);
        const float tA = scale * dA, tB = scale * dB;
        #pragma unroll
        for (int r = 0; r < 8; r++) {
            wA[r] -= tA * v[r];
            wB[r] -= tB * v[r];
        }
    }
    #pragma unroll
    for (int r = 0; r < 8; r++) {
        Wt[wt_idx(ib + r, jA)] = __float2bfloat16(wA[r]);
        Wt[wt_idx(ib + r, jB)] = __float2bfloat16(wB[r]);
    }
}

// ---------------------------------------------------------------------------
// Kernel 2: out[b] = W @ x[b].  BARRIER-FREE / LDS-FREE.
// 512 thr / 8 independent waves; wave w owns a 64o x 64n output tile
// (o = w*64..w*64+63, n = block's 64-col slice).  BM=512 -> x read once.
//   W (B-operand): per-lane dwordx4 from frag-tiled Wt -> VGPR, dist-1
//     prefetch, dbuf.  L2-resident (512 KB), no LDS round-trip.
//   x (A-operand): per-lane 8-dword k-gather (4 rows x 64 B per instr,
//     coalesced) -> fp32 reg ring (dist-2 = ~2 steps >= HBM latency),
//     cvt -> bf16 at use.
//   NO __syncthreads, NO manual vmcnt: compiler inserts counted
//     vmcnt-before-use; with no barriers there is nothing to drain.
//   Evidence base: v0-v3 all pinned at 2.7-2.9 TB/s with idle pipes
//     (MfmaUtil 13-16, VALUBusy 7-10) -> per-step sync convoy, not BW.
// Regs: acc 64 + pfA ring 96 + W dbuf 32 + temps -> ~220, bounds(512,2)
// pins <=256 -> 2 waves/SIMD, each self-paced.
// ---------------------------------------------------------------------------
__global__ __launch_bounds__(512, 2) void hh_gemm(
    const float* __restrict__ x,
    const __hip_bfloat16* __restrict__ Wt,
    float* __restrict__ out)
{
    const int tid  = threadIdx.x;
    const int wave = tid >> 6, lane = tid & 63;
    const int quad = lane >> 4, l16 = lane & 15;

    const int bid = blockIdx.x;          // 0..1023
    const int b   = bid >> 6;            // 0..15
    const int nt  = bid & 63;            // 0..63
    const int n0  = nt * BN;

    // A-gather base: row k = kt*32 + quad*8 + e, col = n0 + mi*16 + l16
    const float* xb = x + (size_t)b * CDIM * SDIM + n0 + l16;
    // W frag base for this wave: frags (kt*32 + wave*4 + oi), 16 B per lane
    const short8* wp = (const short8*)Wt + (size_t)wave * 4 * 64 + lane;

    f32x4 acc[4][4];                     // [mi = n-frag][oi = o-frag]
    #pragma unroll
    for (int mi = 0; mi < 4; mi++)
        #pragma unroll
        for (int oi = 0; oi < 4; oi++) {
            f32x4 z = {0.0f, 0.0f, 0.0f, 0.0f};
            acc[mi][oi] = z;
        }

    float  pfA[3][4][8];                 // dist-2 ring: [slot][mi][e]
    short8 wb[2][4];                     // dist-1 dbuf: [slot][oi]

    auto loadA = [&](int kt, int s) {
        const float* p = xb + (size_t)(kt * BK + quad * 8) * SDIM;
        #pragma unroll
        for (int mi = 0; mi < 4; mi++)
            #pragma unroll
            for (int e = 0; e < 8; e++)
                pfA[s][mi][e] = p[(size_t)e * SDIM + mi * 16];
    };
    auto loadW = [&](int kt, int s) {
        const short8* p = wp + (size_t)kt * 32 * 64;
        #pragma unroll
        for (int oi = 0; oi < 4; oi++)
            wb[s][oi] = p[oi * 64];
    };

    // ---- prologue: A(0),A(1) in flight (dist-2), W(0) in flight ----
    loadA(0, 0);
    loadW(0, 0);
    loadA(1, 1);

    #pragma unroll
    for (int kt = 0; kt < NSTEP; kt++) {
        if (kt + 1 < NSTEP) loadW(kt + 1, (kt + 1) & 1);
        if (kt + 2 < NSTEP) loadA(kt + 2, (kt + 2) % 3);
        const int s = kt % 3, w = kt & 1;
        #pragma unroll
        for (int mi = 0; mi < 4; mi++) {
            short8 afr;
            #pragma unroll
            for (int e = 0; e < 8; e++) {
                __hip_bfloat16 h = __float2bfloat16(pfA[s][mi][e]);
                afr[e] = *(const short*)&h;
            }
            #pragma unroll
            for (int oi = 0; oi < 4; oi++)
                acc[mi][oi] = __builtin_amdgcn_mfma_f32_16x16x32_bf16(
                    afr, wb[w][oi], acc[mi][oi], 0, 0, 0);
        }
    }

    // ---- epilogue: D col(o) = l16, row(spatial) = quad*4 + r -> float4 ----
    float* ob = out + (size_t)b * CDIM * SDIM + n0;
    #pragma unroll
    for (int oi = 0; oi < 4; oi++) {
        const int o = wave * 64 + oi * 16 + l16;
        #pragma unroll
        for (int mi = 0; mi < 4; mi++)
            *(f32x4*)(ob + (size_t)o * SDIM + mi * 16 + quad * 4) = acc[mi][oi];
    }
}

// ---------------------------------------------------------------------------
extern "C" void kernel_launch(void* const* d_in, const int* in_sizes, int n_in,
                              void* d_out, int out_size, void* d_ws, size_t ws_size,
                              hipStream_t stream) {
    const float* x = (const float*)d_in[0];   // [16, 512, 64, 64]
    const float* V = (const float*)d_in[1];   // [32, 512]
    float* out = (float*)d_out;               // [16, 512, 64, 64] fp32

    __hip_bfloat16* Wt = (__hip_bfloat16*)d_ws;   // 512 KB frag-tiled W

    compute_w<<<64, 256, 0, stream>>>(V, Wt);
    hh_gemm<<<1024, 512, 0, stream>>>(x, Wt, out);
}

// Round 5
// 278.623 us; speedup vs baseline: 1.1340x; 1.1340x over previous
//
#include <hip/hip_runtime.h>
#include <hip/hip_bf16.h>
#include <stdint.h>
#include <stddef.h>

#define HH_EPS 1e-8f

typedef __attribute__((ext_vector_type(8))) short short8;
typedef __attribute__((ext_vector_type(4))) short short4_t;
typedef __attribute__((ext_vector_type(4))) float f32x4;

#define CDIM 512
#define SDIM 4096
#define BN 64
#define BK 32
#define NSTEP 16      // CDIM / BK

// ---------------------------------------------------------------------------
// Frag-tiled W (blocking-agnostic): fragment id = (c>>5)*32 + (o>>4);
// within a fragment: lane = ((c>>3)&3)*16 + (o&15), elem = c&7.
// Fragment = 64 lanes x 16 B = 1 KB contiguous in exact B-operand lane order
// -> one dwordx4 per lane loads a whole MFMA B-fragment (no LDS needed).
// ---------------------------------------------------------------------------
__device__ __forceinline__ size_t wt_idx(int o, int c) {
    return (((size_t)(c >> 5) * 32 + (o >> 4)) * 64
            + (size_t)((c >> 3) & 3) * 16 + (o & 15)) * 8 + (c & 7);
}

// ---------------------------------------------------------------------------
// Kernel 1: W = H_32 ... H_1, column-parallel, on-the-fly normalization.
// ---------------------------------------------------------------------------
__global__ void compute_w(const float* __restrict__ V,
                          __hip_bfloat16* __restrict__ Wt) {
    const int wave = threadIdx.x >> 6;
    const int lane = threadIdx.x & 63;
    const int jA = (blockIdx.x * 4 + wave) * 2;
    const int jB = jA + 1;
    const int ib = lane * 8;

    float wA[8], wB[8];
    #pragma unroll
    for (int r = 0; r < 8; r++) {
        wA[r] = (ib + r == jA) ? 1.0f : 0.0f;
        wB[r] = (ib + r == jB) ? 1.0f : 0.0f;
    }
    float4 c0 = *(const float4*)(V + ib);
    float4 c1 = *(const float4*)(V + ib + 4);

    for (int k = 0; k < 32; k++) {
        const float v[8] = {c0.x, c0.y, c0.z, c0.w, c1.x, c1.y, c1.z, c1.w};
        if (k < 31) {
            c0 = *(const float4*)(V + (size_t)(k + 1) * 512 + ib);
            c1 = *(const float4*)(V + (size_t)(k + 1) * 512 + ib + 4);
        }
        float dA = 0.0f, dB = 0.0f, ss = 0.0f;
        #pragma unroll
        for (int r = 0; r < 8; r++) {
            dA += v[r] * wA[r];
            dB += v[r] * wB[r];
            ss += v[r] * v[r];
        }
        #pragma unroll
        for (int off = 32; off > 0; off >>= 1) {
            dA += __shfl_xor(dA, off);
            dB += __shfl_xor(dB, off);
            ss += __shfl_xor(ss, off);
        }
        const float t = sqrtf(ss) + HH_EPS;
        const float scale = 2.0f / (t * t);
        const float tA = scale * dA, tB = scale * dB;
        #pragma unroll
        for (int r = 0; r < 8; r++) {
            wA[r] -= tA * v[r];
            wB[r] -= tB * v[r];
        }
    }
    #pragma unroll
    for (int r = 0; r < 8; r++) {
        Wt[wt_idx(ib + r, jA)] = __float2bfloat16(wA[r]);
        Wt[wt_idx(ib + r, jB)] = __float2bfloat16(wB[r]);
    }
}

__device__ __forceinline__ void lds_barrier() {
    // lgkmcnt(0) only: my LDS ops retired; global loads stay in flight
    // (compiler inserts exact vmcnt waits at each register use).
    __builtin_amdgcn_s_waitcnt(0xC07F);
    __builtin_amdgcn_s_barrier();
}

// ---------------------------------------------------------------------------
// Kernel 2: out[b] = W @ x[b].  MINIMAL-STATE for the 16-waves/CU reg tier.
// 512 thr / 8 waves; wave w owns 64o x 64n (acc 4x4 f32x4 = 64 AGPR).
// BM=512 -> x read ONCE; BN=64; grid 1024 -> 2 independent blocks/CU.
//   W: wave-private frags straight from L2 (1 dwordx4/lane/frag, 16 VGPR,
//      single-buffered, loaded for kt+1 after kt's MFMAs). No LDS, no DMA,
//      no vmcnt gate in the barrier path.
//   x: 4 dwords/thread (coalesced 256 B/wave-instr) -> pfB[2][4] (8 VGPR,
//      dist-2) -> cvt -> frag-ordered bf16 LDS dbuf 2x4 KB (b128 reads,
//      conflict-free). Barrier is lgkm-only.
// Evidence: v0-v4 all allocated >128 unified regs -> 8 waves/CU tier ->
// 1.4-2.9 TB/s with all pipes idle. This version is engineered to <=128.
// ---------------------------------------------------------------------------
__global__ __launch_bounds__(512, 4) void hh_gemm(
    const float* __restrict__ x,
    const __hip_bfloat16* __restrict__ Wt,
    float* __restrict__ out)
{
    __shared__ __attribute__((aligned(16))) __hip_bfloat16 Bbuf[2][BN * BK]; // 2 x 4 KB

    const int tid  = threadIdx.x;
    const int wave = tid >> 6, lane = tid & 63;
    const int quad = lane >> 4, l16 = lane & 15;

    const int bid = blockIdx.x;          // 0..1023
    const int b   = bid >> 6;            // 0..15
    const int nt  = bid & 63;            // 0..63
    const int n0  = nt * BN;

    // x staging ownership: col bn, k-slot kh -> rows kq*8 + h*4 + j (j=0..3)
    const int bn = tid & 63;
    const int kh = tid >> 6;             // 0..7
    const int kq_s = kh >> 1, h_s = kh & 1;
    const float* xp0 = x + (size_t)b * CDIM * SDIM
                         + (size_t)(kq_s * 8 + h_s * 4) * SDIM + n0 + bn;

    // W frags: wave-private; frag id = kt*32 + wave*4 + oi
    const short8* wp = (const short8*)Wt + (size_t)wave * 4 * 64 + lane;

    f32x4 acc[4][4];                     // [mi = n-frag][oi = o-frag]
    #pragma unroll
    for (int mi = 0; mi < 4; mi++)
        #pragma unroll
        for (int oi = 0; oi < 4; oi++) {
            f32x4 z = {0.0f, 0.0f, 0.0f, 0.0f};
            acc[mi][oi] = z;
        }

    float  pfB[2][4];                    // dist-2 x stage (8 VGPR)
    short8 wb[4];                        // current W frags (16 VGPR)

    auto loadB = [&](int kt, int s) {
        const float* p = xp0 + (size_t)kt * BK * SDIM;
        #pragma unroll
        for (int j = 0; j < 4; j++) pfB[s][j] = p[(size_t)j * SDIM];
    };
    auto writeB = [&](int buf, int s) {
        short4_t pk;
        #pragma unroll
        for (int j = 0; j < 4; j++) {
            __hip_bfloat16 h = __float2bfloat16(pfB[s][j]);
            pk[j] = *(const short*)&h;
        }
        // frag-order: frag = bn>>4 (n-16-group); lane = kq*16 + (bn&15);
        // elems = h*4 .. h*4+3  (bf16 units; 8 B aligned)
        *(short4_t*)(&Bbuf[buf][(size_t)(bn >> 4) * 512
                                + (size_t)(kq_s * 16 + (bn & 15)) * 8
                                + h_s * 4]) = pk;
    };
    auto loadW = [&](int kt) {
        const short8* p = wp + (size_t)kt * 32 * 64;
        #pragma unroll
        for (int oi = 0; oi < 4; oi++) wb[oi] = p[oi * 64];
    };

    // ---- prologue: B(0),B(1) in flight; W(0) in flight; B(0) -> LDS0 ----
    loadB(0, 0);
    loadB(1, 1);
    loadW(0);
    writeB(0, 0);         // compiler vmcnt retires B(0) only; B(1),W(0) fly
    lds_barrier();

    #pragma unroll
    for (int kt = 0; kt < NSTEP; kt++) {
        if (kt + 2 < NSTEP) loadB(kt + 2, kt & 1);   // slot freed last step
        const int p = kt & 1;
        #pragma unroll
        for (int mi = 0; mi < 4; mi++) {
            const short8 afr =
                *(const short8*)(&Bbuf[p][(size_t)(mi * 64 + lane) * 8]);
            #pragma unroll
            for (int oi = 0; oi < 4; oi++)
                acc[mi][oi] = __builtin_amdgcn_mfma_f32_16x16x32_bf16(
                    afr, wb[oi], acc[mi][oi], 0, 0, 0);
        }
        if (kt + 1 < NSTEP) {
            loadW(kt + 1);              // reuse wb after last MFMA use
            writeB(p ^ 1, (kt + 1) & 1);
            lds_barrier();
        }
    }

    // ---- epilogue: D col = o (l16), reg axis = contiguous n -> float4 ----
    float* ob = out + (size_t)b * CDIM * SDIM + n0;
    #pragma unroll
    for (int oi = 0; oi < 4; oi++) {
        const int o = wave * 64 + oi * 16 + l16;
        #pragma unroll
        for (int mi = 0; mi < 4; mi++)
            *(f32x4*)(ob + (size_t)o * SDIM + mi * 16 + quad * 4) = acc[mi][oi];
    }
}

// ---------------------------------------------------------------------------
extern "C" void kernel_launch(void* const* d_in, const int* in_sizes, int n_in,
                              void* d_out, int out_size, void* d_ws, size_t ws_size,
                              hipStream_t stream) {
    const float* x = (const float*)d_in[0];   // [16, 512, 64, 64]
    const float* V = (const float*)d_in[1];   // [32, 512]
    float* out = (float*)d_out;               // [16, 512, 64, 64] fp32

    __hip_bfloat16* Wt = (__hip_bfloat16*)d_ws;   // 512 KB frag-tiled W

    compute_w<<<64, 256, 0, stream>>>(V, Wt);
    hh_gemm<<<1024, 512, 0, stream>>>(x, Wt, out);
}

// Round 6
// 265.635 us; speedup vs baseline: 1.1895x; 1.0489x over previous
//
#include <hip/hip_runtime.h>
#include <hip/hip_bf16.h>
#include <stdint.h>
#include <stddef.h>

#define HH_EPS 1e-8f

typedef __attribute__((ext_vector_type(8))) short short8;
typedef __attribute__((ext_vector_type(4))) short short4_t;
typedef __attribute__((ext_vector_type(4))) float f32x4;

#define CDIM 512
#define SDIM 4096
#define BN 128
#define BK 32
#define NSTEP 16      // CDIM / BK

// ---------------------------------------------------------------------------
// Frag-tiled W (blocking-agnostic): fragment id = (c>>5)*32 + (o>>4);
// within a fragment: lane = ((c>>3)&3)*16 + (o&15), elem = c&7.
// Fragment = 64 lanes x 16 B = 1 KB contiguous in exact B-operand lane order
// -> one dwordx4 per lane loads a whole MFMA B-fragment (no LDS needed).
// ---------------------------------------------------------------------------
__device__ __forceinline__ size_t wt_idx(int o, int c) {
    return (((size_t)(c >> 5) * 32 + (o >> 4)) * 64
            + (size_t)((c >> 3) & 3) * 16 + (o & 15)) * 8 + (c & 7);
}

// ---------------------------------------------------------------------------
// Kernel 1: W = H_32 ... H_1, column-parallel, on-the-fly normalization.
// ---------------------------------------------------------------------------
__global__ void compute_w(const float* __restrict__ V,
                          __hip_bfloat16* __restrict__ Wt) {
    const int wave = threadIdx.x >> 6;
    const int lane = threadIdx.x & 63;
    const int jA = (blockIdx.x * 4 + wave) * 2;
    const int jB = jA + 1;
    const int ib = lane * 8;

    float wA[8], wB[8];
    #pragma unroll
    for (int r = 0; r < 8; r++) {
        wA[r] = (ib + r == jA) ? 1.0f : 0.0f;
        wB[r] = (ib + r == jB) ? 1.0f : 0.0f;
    }
    float4 c0 = *(const float4*)(V + ib);
    float4 c1 = *(const float4*)(V + ib + 4);

    for (int k = 0; k < 32; k++) {
        const float v[8] = {c0.x, c0.y, c0.z, c0.w, c1.x, c1.y, c1.z, c1.w};
        if (k < 31) {
            c0 = *(const float4*)(V + (size_t)(k + 1) * 512 + ib);
            c1 = *(const float4*)(V + (size_t)(k + 1) * 512 + ib + 4);
        }
        float dA = 0.0f, dB = 0.0f, ss = 0.0f;
        #pragma unroll
        for (int r = 0; r < 8; r++) {
            dA += v[r] * wA[r];
            dB += v[r] * wB[r];
            ss += v[r] * v[r];
        }
        #pragma unroll
        for (int off = 32; off > 0; off >>= 1) {
            dA += __shfl_xor(dA, off);
            dB += __shfl_xor(dB, off);
            ss += __shfl_xor(ss, off);
        }
        const float t = sqrtf(ss) + HH_EPS;
        const float scale = 2.0f / (t * t);
        const float tA = scale * dA, tB = scale * dB;
        #pragma unroll
        for (int r = 0; r < 8; r++) {
            wA[r] -= tA * v[r];
            wB[r] -= tB * v[r];
        }
    }
    #pragma unroll
    for (int r = 0; r < 8; r++) {
        Wt[wt_idx(ib + r, jA)] = __float2bfloat16(wA[r]);
        Wt[wt_idx(ib + r, jB)] = __float2bfloat16(wB[r]);
    }
}

__device__ __forceinline__ void lds_barrier() {
    // lgkmcnt(0) only: my LDS ops retired; global loads stay in flight
    // (compiler inserts exact vmcnt waits at each register use).
    __builtin_amdgcn_s_waitcnt(0xC07F);
    __builtin_amdgcn_s_barrier();
}

// ---------------------------------------------------------------------------
// Kernel 2: out[b] = W @ x[b].  CONCURRENCY-MAX design:
//   evidence v0-v5: time ~ per-CU VMEM bytes / (waves x bytes-in-flight);
//   all prior variants plateau at 9-15 B/cyc/CU with idle pipes.
// 1024 thr / 16 waves per block (16 waves/CU resident, 2x v2), wave =
// 32o x 128n (acc 2x8 f32x4 = 64 AGPR -> block stays in <=128-reg tier).
// BN=128 -> W restream = 1 MB/CU (v2's minimum); BM=512 -> x read once.
//   W: direct L2->VGPR dwordx4 frags, DOUBLE-buffered (fixes v5's per-step
//      serialized W wait: loadW(kt+1) issues at step start, hides under
//      MFMAs + LDS reads).  No LDS for W, no DMA, no vmcnt gate.
//   x: 4 dword k-gather/thread -> dist-2 reg ring -> cvt -> frag-ordered
//      bf16 LDS dbuf (2 x 8 KB), conflict-free b128 reads, lgkm-only barrier.
// ---------------------------------------------------------------------------
__global__ __launch_bounds__(1024, 4) void hh_gemm(
    const float* __restrict__ x,
    const __hip_bfloat16* __restrict__ Wt,
    float* __restrict__ out)
{
    __shared__ __attribute__((aligned(16))) __hip_bfloat16 Bbuf[2][BN * BK]; // 2 x 8 KB

    const int tid  = threadIdx.x;
    const int wave = tid >> 6, lane = tid & 63;
    const int quad = lane >> 4, l16 = lane & 15;

    const int bid = blockIdx.x;          // 0..511
    const int b   = bid >> 5;            // 0..15
    const int nt  = bid & 31;            // 0..31
    const int n0  = nt * BN;

    // x staging: col c = tid&127; rows r = (tid>>7)*4 + j, j=0..3
    const int c_s  = tid & 127;
    const int r0_s = (tid >> 7) * 4;                 // 0,4,8,...,28
    const int kq_s = tid >> 8;                       // r>>3  (0..3)
    const int h_s  = (tid >> 7) & 1;                 // (r>>2)&1
    const float* xp0 = x + (size_t)b * CDIM * SDIM
                         + (size_t)r0_s * SDIM + n0 + c_s;

    // W frags: wave w owns o-rows w*32..w*32+31 -> frag ids kt*32 + w*2 + oi
    const short8* wp = (const short8*)Wt + (size_t)(wave * 2) * 64 + lane;

    f32x4 acc[8][2];                     // [mi = n-frag][oi = o-frag]
    #pragma unroll
    for (int mi = 0; mi < 8; mi++)
        #pragma unroll
        for (int oi = 0; oi < 2; oi++) {
            f32x4 z = {0.0f, 0.0f, 0.0f, 0.0f};
            acc[mi][oi] = z;
        }

    float  pfB[2][4];                    // dist-2 x stage (8 VGPR)
    short8 wb[2][2];                     // dist-1 W dbuf (16 VGPR)

    auto loadB = [&](int kt, int s) {
        const float* p = xp0 + (size_t)kt * BK * SDIM;
        #pragma unroll
        for (int j = 0; j < 4; j++) pfB[s][j] = p[(size_t)j * SDIM];
    };
    auto writeB = [&](int buf, int s) {
        short4_t pk;
        #pragma unroll
        for (int j = 0; j < 4; j++) {
            __hip_bfloat16 h = __float2bfloat16(pfB[s][j]);
            pk[j] = *(const short*)&h;
        }
        // frag g = c>>4 (1 KB each); lane = kq*16 + (c&15); elems h*4..h*4+3
        *(short4_t*)(&Bbuf[buf][(size_t)(c_s >> 4) * 512
                                + (size_t)(kq_s * 16 + (c_s & 15)) * 8
                                + h_s * 4]) = pk;
    };
    auto loadW = [&](int kt, int s) {
        const short8* p = wp + (size_t)kt * 32 * 64;
        wb[s][0] = p[0];
        wb[s][1] = p[64];
    };

    // ---- prologue: B(0),B(1) + W(0) in flight; B(0) -> LDS0 ----
    loadB(0, 0);
    loadB(1, 1);
    loadW(0, 0);
    writeB(0, 0);         // compiler vmcnt retires B(0); B(1),W(0) stay out
    lds_barrier();

    #pragma unroll
    for (int kt = 0; kt < NSTEP; kt++) {
        const int p = kt & 1, w = kt & 1;
        if (kt + 1 < NSTEP) loadW(kt + 1, w ^ 1);    // hides under this step
        if (kt + 2 < NSTEP) loadB(kt + 2, kt & 1);   // ring slot freed
        #pragma unroll
        for (int mi = 0; mi < 8; mi++) {
            const short8 afr =
                *(const short8*)(&Bbuf[p][(size_t)(mi * 64 + lane) * 8]);
            #pragma unroll
            for (int oi = 0; oi < 2; oi++)
                acc[mi][oi] = __builtin_amdgcn_mfma_f32_16x16x32_bf16(
                    afr, wb[w][oi], acc[mi][oi], 0, 0, 0);
        }
        if (kt + 1 < NSTEP) {
            writeB(p ^ 1, (kt + 1) & 1);
            lds_barrier();
        }
    }

    // ---- epilogue: D col = o (l16), reg axis = contiguous n -> float4 ----
    float* ob = out + (size_t)b * CDIM * SDIM + n0;
    #pragma unroll
    for (int oi = 0; oi < 2; oi++) {
        const int o = wave * 32 + oi * 16 + l16;
        #pragma unroll
        for (int mi = 0; mi < 8; mi++)
            *(f32x4*)(ob + (size_t)o * SDIM + mi * 16 + quad * 4) = acc[mi][oi];
    }
}

// ---------------------------------------------------------------------------
extern "C" void kernel_launch(void* const* d_in, const int* in_sizes, int n_in,
                              void* d_out, int out_size, void* d_ws, size_t ws_size,
                              hipStream_t stream) {
    const float* x = (const float*)d_in[0];   // [16, 512, 64, 64]
    const float* V = (const float*)d_in[1];   // [32, 512]
    float* out = (float*)d_out;               // [16, 512, 64, 64] fp32

    __hip_bfloat16* Wt = (__hip_bfloat16*)d_ws;   // 512 KB frag-tiled W

    compute_w<<<64, 256, 0, stream>>>(V, Wt);
    hh_gemm<<<512, 1024, 0, stream>>>(x, Wt, out);
}

// Round 7
// 264.680 us; speedup vs baseline: 1.1938x; 1.0036x over previous
//
#include <hip/hip_runtime.h>
#include <hip/hip_bf16.h>
#include <stdint.h>
#include <stddef.h>

#define HH_EPS 1e-8f

typedef __attribute__((ext_vector_type(8))) short short8;
typedef __attribute__((ext_vector_type(4))) float f32x4;

#define CDIM 512
#define SDIM 4096
#define BN 128
#define BK 64
#define NSTEP 8       // CDIM / BK

// ---------------------------------------------------------------------------
// Frag-tiled W (blocking-agnostic): fragment id = (c>>5)*32 + (o>>4);
// within a fragment: lane = ((c>>3)&3)*16 + (o&15), elem = c&7.
// Fragment = 64 lanes x 16 B = 1 KB contiguous in exact B-operand lane order
// -> one dwordx4 per lane loads a whole MFMA B-fragment (no LDS needed).
// ---------------------------------------------------------------------------
__device__ __forceinline__ size_t wt_idx(int o, int c) {
    return (((size_t)(c >> 5) * 32 + (o >> 4)) * 64
            + (size_t)((c >> 3) & 3) * 16 + (o & 15)) * 8 + (c & 7);
}

// ---------------------------------------------------------------------------
// Kernel 1: W = H_32 ... H_1, column-parallel, on-the-fly normalization.
// ---------------------------------------------------------------------------
__global__ void compute_w(const float* __restrict__ V,
                          __hip_bfloat16* __restrict__ Wt) {
    const int wave = threadIdx.x >> 6;
    const int lane = threadIdx.x & 63;
    const int jA = (blockIdx.x * 4 + wave) * 2;
    const int jB = jA + 1;
    const int ib = lane * 8;

    float wA[8], wB[8];
    #pragma unroll
    for (int r = 0; r < 8; r++) {
        wA[r] = (ib + r == jA) ? 1.0f : 0.0f;
        wB[r] = (ib + r == jB) ? 1.0f : 0.0f;
    }
    float4 c0 = *(const float4*)(V + ib);
    float4 c1 = *(const float4*)(V + ib + 4);

    for (int k = 0; k < 32; k++) {
        const float v[8] = {c0.x, c0.y, c0.z, c0.w, c1.x, c1.y, c1.z, c1.w};
        if (k < 31) {
            c0 = *(const float4*)(V + (size_t)(k + 1) * 512 + ib);
            c1 = *(const float4*)(V + (size_t)(k + 1) * 512 + ib + 4);
        }
        float dA = 0.0f, dB = 0.0f, ss = 0.0f;
        #pragma unroll
        for (int r = 0; r < 8; r++) {
            dA += v[r] * wA[r];
            dB += v[r] * wB[r];
            ss += v[r] * v[r];
        }
        #pragma unroll
        for (int off = 32; off > 0; off >>= 1) {
            dA += __shfl_xor(dA, off);
            dB += __shfl_xor(dB, off);
            ss += __shfl_xor(ss, off);
        }
        const float t = sqrtf(ss) + HH_EPS;
        const float scale = 2.0f / (t * t);
        const float tA = scale * dA, tB = scale * dB;
        #pragma unroll
        for (int r = 0; r < 8; r++) {
            wA[r] -= tA * v[r];
            wB[r] -= tB * v[r];
        }
    }
    #pragma unroll
    for (int r = 0; r < 8; r++) {
        Wt[wt_idx(ib + r, jA)] = __float2bfloat16(wA[r]);
        Wt[wt_idx(ib + r, jB)] = __float2bfloat16(wB[r]);
    }
}

__device__ __forceinline__ void lds_barrier() {
    // lgkmcnt(0) only: my LDS ops retired; global loads stay in flight
    // (compiler inserts exact vmcnt waits at each register use).
    __builtin_amdgcn_s_waitcnt(0xC07F);
    __builtin_amdgcn_s_barrier();
}

// ---------------------------------------------------------------------------
// Kernel 2: out[b] = W @ x[b].  WORK-PER-BARRIER x2 (m233 evidence: 2-phase
// loops are 72% stage+vmcnt+barrier overhead; the dial is work per sync).
// BK=64 -> 8 K-steps, 8 barriers (v6 had 16), 32 MFMA/wave/step, W-frag
// L2 latency amortized 2x.  Tile o512 x n128, 1024 thr / 16 waves, wave =
// o32 x n128 (acc 2x8 f32x4 = 64 AGPR).  bounds(1024,4) pins <=128 unified.
//   W: direct L2->VGPR dwordx4 frags, JIT per kk-half (16 VGPR transient).
//   x: one k-octet per thread (8 dword gather) -> dist-2 reg ring -> cvt ->
//      frag-ordered bf16 LDS (SINGLE b128 write/thread/step; v6's 8 B write
//      conflicts gone), dbuf 2 x 16 KB, lgkm-only barrier.
// ---------------------------------------------------------------------------
__global__ __launch_bounds__(1024, 4) void hh_gemm(
    const float* __restrict__ x,
    const __hip_bfloat16* __restrict__ Wt,
    float* __restrict__ out)
{
    __shared__ __attribute__((aligned(16))) __hip_bfloat16 Bbuf[2][BN * BK]; // 2 x 16 KB

    const int tid  = threadIdx.x;
    const int wave = tid >> 6, lane = tid & 63;
    const int quad = lane >> 4, l16 = lane & 15;

    const int bid = blockIdx.x;          // 0..511
    const int b   = bid >> 5;            // 0..15
    const int nt  = bid & 31;            // 0..31
    const int n0  = nt * BN;

    // x staging: thread owns col c_s and k-octet o8 (8 consecutive k rows)
    const int c_s = tid & 127;           // 0..127
    const int o8  = tid >> 7;            // 0..7
    const float* xp0 = x + (size_t)b * CDIM * SDIM
                         + (size_t)(o8 * 8) * SDIM + n0 + c_s;
    // LDS slot (bf16 units): frag (kk=o8>>2, g=c_s>>4), lane'=(o8&3)*16+(c_s&15)
    const size_t wslot = ((size_t)((o8 >> 2) * 8 + (c_s >> 4)) * 64
                          + (size_t)((o8 & 3) * 16 + (c_s & 15))) * 8;

    // W frags: wave owns o-rows wave*32..+31 -> frag ids kt32*32 + wave*2 + oi
    const short8* wp = (const short8*)Wt + (size_t)(wave * 2) * 64 + lane;

    f32x4 acc[8][2];                     // [mi = n-frag][oi = o-frag]
    #pragma unroll
    for (int mi = 0; mi < 8; mi++)
        #pragma unroll
        for (int oi = 0; oi < 2; oi++) {
            f32x4 z = {0.0f, 0.0f, 0.0f, 0.0f};
            acc[mi][oi] = z;
        }

    float pfB[2][8];                     // dist-2 x stage ring (16 VGPR)

    auto loadB = [&](int kt, int s) {
        const float* p = xp0 + (size_t)kt * BK * SDIM;
        #pragma unroll
        for (int j = 0; j < 8; j++) pfB[s][j] = p[(size_t)j * SDIM];
    };
    auto writeB = [&](int buf, int s) {
        short8 pk;
        #pragma unroll
        for (int j = 0; j < 8; j++) {
            __hip_bfloat16 h = __float2bfloat16(pfB[s][j]);
            pk[j] = *(const short*)&h;
        }
        *(short8*)(&Bbuf[buf][wslot]) = pk;   // one b128 write per step
    };

    // ---- prologue: B(0),B(1) in flight; B(0) -> LDS0 ----
    loadB(0, 0);
    loadB(1, 1);
    writeB(0, 0);         // compiler vmcnt retires B(0); B(1) stays in flight
    lds_barrier();

    #pragma unroll
    for (int kt = 0; kt < NSTEP; kt++) {
        const int p = kt & 1;
        if (kt + 2 < NSTEP) loadB(kt + 2, kt & 1);   // freed ring slot
        #pragma unroll
        for (int kk = 0; kk < 2; kk++) {
            // JIT W frags for this kk-half (16 VGPR transient, L2-hot)
            short8 wf[2];
            const short8* wq = wp + ((size_t)(kt * 2 + kk) * 32) * 64;
            wf[0] = wq[0];
            wf[1] = wq[64];
            #pragma unroll
            for (int mi = 0; mi < 8; mi++) {
                const short8 afr = *(const short8*)(
                    &Bbuf[p][(size_t)((kk * 8 + mi) * 64 + lane) * 8]);
                acc[mi][0] = __builtin_amdgcn_mfma_f32_16x16x32_bf16(
                    afr, wf[0], acc[mi][0], 0, 0, 0);
                acc[mi][1] = __builtin_amdgcn_mfma_f32_16x16x32_bf16(
                    afr, wf[1], acc[mi][1], 0, 0, 0);
            }
        }
        if (kt + 1 < NSTEP) {
            writeB(p ^ 1, (kt + 1) & 1);
            lds_barrier();
        }
    }

    // ---- epilogue: D col = o (l16), reg axis = contiguous n -> float4 ----
    float* ob = out + (size_t)b * CDIM * SDIM + n0;
    #pragma unroll
    for (int oi = 0; oi < 2; oi++) {
        const int o = wave * 32 + oi * 16 + l16;
        #pragma unroll
        for (int mi = 0; mi < 8; mi++)
            *(f32x4*)(ob + (size_t)o * SDIM + mi * 16 + quad * 4) = acc[mi][oi];
    }
}

// ---------------------------------------------------------------------------
extern "C" void kernel_launch(void* const* d_in, const int* in_sizes, int n_in,
                              void* d_out, int out_size, void* d_ws, size_t ws_size,
                              hipStream_t stream) {
    const float* x = (const float*)d_in[0];   // [16, 512, 64, 64]
    const float* V = (const float*)d_in[1];   // [32, 512]
    float* out = (float*)d_out;               // [16, 512, 64, 64] fp32

    __hip_bfloat16* Wt = (__hip_bfloat16*)d_ws;   // 512 KB frag-tiled W

    compute_w<<<64, 256, 0, stream>>>(V, Wt);
    hh_gemm<<<512, 1024, 0, stream>>>(x, Wt, out);
}